// Round 1
// baseline (72.981 us; speedup 1.0000x reference)
//
#include <hip/hip_runtime.h>

// Problem constants (from reference setup_inputs)
#define B_  16
#define T_  4096
#define C_  512
#define K_  4
#define NT_ 64              // chunks along T
#define L_  (T_ / NT_)      // 64 steps per chunk

// a = clip(sigmoid(logit_alpha), 1e-4, 1-1e-4)
__device__ __forceinline__ float sigmoid_clamp(float la) {
    float av = 1.0f / (1.0f + expf(-la));
    return fminf(fmaxf(av, 1e-4f), 1.0f - 1e-4f);
}

// Pass 1: per (b, chunk j, c) compute zero-init partial scans s_k(j).
// ws layout: ws[((b*K + k)*NT + j)*C + c]
__global__ __launch_bounds__(512) void ema_pass1(const float* __restrict__ x,
                                                 const float* __restrict__ logit_alpha,
                                                 float* __restrict__ ws) {
    const int c = threadIdx.x;
    const int b = blockIdx.x / NT_;
    const int j = blockIdx.x % NT_;

    float a[K_], oma[K_], s[K_];
#pragma unroll
    for (int k = 0; k < K_; ++k) {
        float av = sigmoid_clamp(logit_alpha[k * C_ + c]);
        a[k] = av; oma[k] = 1.0f - av; s[k] = 0.0f;
    }

    const float* xp = x + ((size_t)b * T_ + (size_t)j * L_) * C_ + c;
#pragma unroll 4
    for (int i = 0; i < L_; ++i) {
        float xv = xp[(size_t)i * C_];
#pragma unroll
        for (int k = 0; k < K_; ++k)
            s[k] = fmaf(a[k], s[k], oma[k] * xv);
    }

#pragma unroll
    for (int k = 0; k < K_; ++k)
        ws[(((size_t)b * K_ + k) * NT_ + j) * C_ + c] = s[k];
}

// Pass 2: per (b, k, c) sequentially combine chunk summaries into carries.
// In-place: ws[j] := y[j*L - 1] (carry INTO chunk j); carry(0) = x[b,0,c].
__global__ __launch_bounds__(512) void ema_pass2(const float* __restrict__ x,
                                                 const float* __restrict__ logit_alpha,
                                                 float* __restrict__ ws) {
    const int c = threadIdx.x;
    const int b = blockIdx.x / K_;
    const int k = blockIdx.x % K_;

    float av = sigmoid_clamp(logit_alpha[k * C_ + c]);
    // A = a^L, L = 64 = 2^6 -> 6 squarings
    float A = av;
#pragma unroll
    for (int q = 0; q < 6; ++q) A *= A;

    float carry = x[(size_t)b * T_ * C_ + c];   // y[0] seed: y[-1] := x[b,0,c]
    float* wsb = ws + ((size_t)b * K_ + k) * NT_ * C_ + c;
    for (int j = 0; j < NT_; ++j) {
        float sj = wsb[(size_t)j * C_];
        wsb[(size_t)j * C_] = carry;
        carry = fmaf(A, carry, sj);
    }
}

// Pass 3: re-scan each chunk from its carry, mix with softmax weights, write out.
__global__ __launch_bounds__(512) void ema_pass3(const float* __restrict__ x,
                                                 const float* __restrict__ logit_alpha,
                                                 const float* __restrict__ mix_logits,
                                                 const float* __restrict__ ws,
                                                 float* __restrict__ out) {
    const int c = threadIdx.x;
    const int b = blockIdx.x / NT_;
    const int j = blockIdx.x % NT_;

    float a[K_], oma[K_], y[K_], m[K_];
#pragma unroll
    for (int k = 0; k < K_; ++k) {
        float av = sigmoid_clamp(logit_alpha[k * C_ + c]);
        a[k] = av; oma[k] = 1.0f - av;
        y[k] = ws[(((size_t)b * K_ + k) * NT_ + j) * C_ + c];
    }

    // softmax over mix_logits[c][0..K)
    float mx = -INFINITY;
#pragma unroll
    for (int k = 0; k < K_; ++k) { m[k] = mix_logits[(size_t)c * K_ + k]; mx = fmaxf(mx, m[k]); }
    float den = 0.0f;
#pragma unroll
    for (int k = 0; k < K_; ++k) { m[k] = expf(m[k] - mx); den += m[k]; }
    float inv = 1.0f / den;
#pragma unroll
    for (int k = 0; k < K_; ++k) m[k] *= inv;

    const float* xp = x + ((size_t)b * T_ + (size_t)j * L_) * C_ + c;
    float*       op = out + ((size_t)b * T_ + (size_t)j * L_) * C_ + c;
#pragma unroll 4
    for (int i = 0; i < L_; ++i) {
        float xv = xp[(size_t)i * C_];
        float acc = 0.0f;
#pragma unroll
        for (int k = 0; k < K_; ++k) {
            y[k] = fmaf(a[k], y[k], oma[k] * xv);
            acc = fmaf(m[k], y[k], acc);
        }
        op[(size_t)i * C_] = acc;
    }
}

extern "C" void kernel_launch(void* const* d_in, const int* in_sizes, int n_in,
                              void* d_out, int out_size, void* d_ws, size_t ws_size,
                              hipStream_t stream) {
    const float* x           = (const float*)d_in[0];
    const float* logit_alpha = (const float*)d_in[1];
    const float* mix_logits  = (const float*)d_in[2];
    float* out = (float*)d_out;
    float* ws  = (float*)d_ws;   // needs B*K*NT*C*4 = 8 MiB

    ema_pass1<<<B_ * NT_, 512, 0, stream>>>(x, logit_alpha, ws);
    ema_pass2<<<B_ * K_,  512, 0, stream>>>(x, logit_alpha, ws);
    ema_pass3<<<B_ * NT_, 512, 0, stream>>>(x, logit_alpha, mix_logits, ws, out);
}